// Round 10
// baseline (1920.250 us; speedup 1.0000x reference)
//
#include <hip/hip_runtime.h>
#include <stdint.h>

#define N_ACTIVE 200000
#define N_IN 64
#define N_OUT 64
#define K_FILT 27
#define R_PAIRS 100000
#define TOTP (K_FILT * R_PAIRS)          // 2,700,000
#define RB 128                           // output rows per block
#define NB ((N_ACTIVE + RB - 1) / RB)    // 1563
#define NBUCK (NB * K_FILT)              // 42,201
#define ELDS 2304
#define MAXG 256
#define MARGIN 4096

#define CF_BLOCKS (N_ACTIVE * N_IN / 8 / 256)    // 6250
#define CW_BLOCKS K_FILT
#define HI_BLOCKS ((TOTP + 255) / 256)

typedef __bf16 bf16x8 __attribute__((ext_vector_type(8)));
typedef float f32x4 __attribute__((ext_vector_type(4)));

__global__ __launch_bounds__(256) void zero_ints(int* __restrict__ p, int n) {
    int i = blockIdx.x * 256 + threadIdx.x;
    if (i < n) p[i] = 0;
}

// ---------------------------------------------------------------------------
// fused prep: convert_feat | convert_wt | dual histogram (out-bucket, in-row)
// ---------------------------------------------------------------------------
__global__ __launch_bounds__(256) void prep_fused(
    const float* __restrict__ feat, __bf16* __restrict__ featb,
    const float* __restrict__ wsrc, __bf16* __restrict__ wt,
    const int* __restrict__ out_idx, const int* __restrict__ in_idx,
    int* __restrict__ cntO, int* __restrict__ cntI)
{
    int bb = blockIdx.x, t = threadIdx.x;
    if (bb < CF_BLOCKS) {
        int i = bb * 256 + t;
        const f32x4* src = reinterpret_cast<const f32x4*>(feat) + 2 * (size_t)i;
        f32x4 v0 = __builtin_nontemporal_load(src);
        f32x4 v1 = __builtin_nontemporal_load(src + 1);
        bf16x8 o;
        o[0] = (__bf16)v0[0]; o[1] = (__bf16)v0[1]; o[2] = (__bf16)v0[2]; o[3] = (__bf16)v0[3];
        o[4] = (__bf16)v1[0]; o[5] = (__bf16)v1[1]; o[6] = (__bf16)v1[2]; o[7] = (__bf16)v1[3];
        reinterpret_cast<bf16x8*>(featb)[i] = o;
    } else if (bb < CF_BLOCKS + CW_BLOCKS) {
        int kf = bb - CF_BLOCKS;
        const float* wk = wsrc + kf * 4096;
        __bf16* wo = wt + kf * 4096;
        int o = t >> 2, i0 = (t & 3) * 16;
        bf16x8 a, b;
        #pragma unroll
        for (int j = 0; j < 8; ++j) a[j] = (__bf16)wk[(i0 + j) * 64 + o];
        #pragma unroll
        for (int j = 0; j < 8; ++j) b[j] = (__bf16)wk[(i0 + 8 + j) * 64 + o];
        *reinterpret_cast<bf16x8*>(wo + o * 64 + i0) = a;
        *reinterpret_cast<bf16x8*>(wo + o * 64 + i0 + 8) = b;
    } else {
        int p = (bb - CF_BLOCKS - CW_BLOCKS) * 256 + t;
        if (p < TOTP) {
            unsigned k = (unsigned)p / (unsigned)R_PAIRS;
            int b = (out_idx[p] >> 7) * K_FILT + (int)k;
            atomicAdd(&cntO[b], 1);
            if (cntI) atomicAdd(&cntI[in_idx[p]], 1);
        }
    }
}

// ---- generic 2-level exclusive scan (1024 elems per block, 4/thread) ----
__global__ __launch_bounds__(256) void scanA(const int* __restrict__ cnt,
                                             int* __restrict__ off,
                                             int* __restrict__ bsum, int n) {
    __shared__ int s[256];
    int t = threadIdx.x, base = blockIdx.x * 1024 + t * 4;
    int v[4], sum = 0;
    #pragma unroll
    for (int j = 0; j < 4; ++j) { v[j] = (base + j < n) ? cnt[base + j] : 0; sum += v[j]; }
    s[t] = sum;
    __syncthreads();
    #pragma unroll
    for (int d = 1; d < 256; d <<= 1) {
        int x = (t >= d) ? s[t - d] : 0;
        __syncthreads();
        s[t] += x;
        __syncthreads();
    }
    int run = s[t] - sum;
    #pragma unroll
    for (int j = 0; j < 4; ++j) { if (base + j < n) off[base + j] = run; run += v[j]; }
    if (t == 255) bsum[blockIdx.x] = s[255];
}

__global__ __launch_bounds__(256) void scanB(int* __restrict__ bsum, int nb) {
    __shared__ int s[256];
    int t = threadIdx.x;
    int v = (t < nb) ? bsum[t] : 0;
    s[t] = v;
    __syncthreads();
    #pragma unroll
    for (int d = 1; d < 256; d <<= 1) {
        int x = (t >= d) ? s[t - d] : 0;
        __syncthreads();
        s[t] += x;
        __syncthreads();
    }
    if (t < nb) bsum[t] = s[t] - v;
}

__global__ __launch_bounds__(256) void scanC(int* __restrict__ off,
                                             const int* __restrict__ bsum,
                                             int* __restrict__ cursor,
                                             int n, int total) {
    int base = blockIdx.x * 1024 + threadIdx.x * 4;
    int add = bsum[blockIdx.x];
    #pragma unroll
    for (int j = 0; j < 4; ++j) {
        int i = base + j;
        if (i < n) { int v = off[i] + add; off[i] = v; cursor[i] = v; }
    }
    if (base == 0) off[n] = total;
}

// ---------------------------------------------------------------------------
// scatter: out-sorted entries + in-sorted destination list (iEnt[j] = G pos)
// entry packed (in_row << 7) | out_local
// ---------------------------------------------------------------------------
__global__ __launch_bounds__(256) void scatter_pack(const int* __restrict__ in_idx,
                                                    const int* __restrict__ out_idx,
                                                    int* __restrict__ cursO,
                                                    int* __restrict__ entries,
                                                    int* __restrict__ cursI,
                                                    int* __restrict__ iEnt) {
    int p = blockIdx.x * 256 + threadIdx.x;
    if (p >= TOTP) return;
    unsigned k = (unsigned)p / (unsigned)R_PAIRS;
    int orow = out_idx[p];
    int iv = in_idx[p];
    int bkt = (orow >> 7) * K_FILT + (int)k;
    int pos = atomicAdd(&cursO[bkt], 1);
    entries[pos] = (iv << 7) | (orow & 127);
    if (iEnt) {
        int jpos = atomicAdd(&cursI[iv], 1);
        iEnt[jpos] = pos;
    }
}

// ---------------------------------------------------------------------------
// pass p gather: stream featb sequentially; scatter rows whose destination
// position lies in [Plo, PhiCov) into G (fire-and-forget 128-B writes).
// ---------------------------------------------------------------------------
__global__ __launch_bounds__(256) void gatherG(const __bf16* __restrict__ featb,
                                               const int* __restrict__ offI,
                                               const int* __restrict__ iEnt,
                                               __bf16* __restrict__ G,
                                               int Plo, int PhiCov) {
    int t = threadIdx.x;
    int row = blockIdx.x * 32 + (t >> 3);
    int q = t & 7;
    if (row >= N_ACTIVE) return;
    bf16x8 v = *reinterpret_cast<const bf16x8*>(featb + (size_t)row * 64 + q * 8);
    int r0 = offI[row], r1 = offI[row + 1];
    for (int d = r0; d < r1; ++d) {
        int dst = iEnt[d];
        if (dst >= Plo && dst < PhiCov)
            __builtin_nontemporal_store(v,
                reinterpret_cast<bf16x8*>(G + (size_t)(dst - Plo) * 64 + q * 8));
    }
}

// ---------------------------------------------------------------------------
// conv pass: block runs iff its entry-range start is in [Plo, Phi). A-frags
// stream sequentially from G (2 KB contiguous per group); per-block fallback
// to featb gather if range exceeds gatherG coverage (P~0, adversarial-safe).
// MFMA layouts r3-verified: A row=lane&15,k=(lane>>4)*8; C/D col=lane&15,
// row=(lane>>4)*4+reg. LDS ds_add scatter epilogue.
// ---------------------------------------------------------------------------
__global__ __launch_bounds__(256) void conv_dense(
    const __bf16* __restrict__ featb,
    const __bf16* __restrict__ G,
    const __bf16* __restrict__ wtb,
    const float* __restrict__ bias,
    const int* __restrict__ off,        // [NBUCK+1]
    const int* __restrict__ entries,    // [TOTP] packed
    float* __restrict__ out,
    int useG, int Plo, int Phi, int PhiCov)
{
    const int b = blockIdx.x;
    const int bK = b * K_FILT;
    if (useG) {
        int s0 = off[bK];
        if (s0 < Plo || s0 >= Phi) return;   // uniform: not this pass's block
    }

    __shared__ float outT[RB][68];      // 34,816 B
    __shared__ int   eLds[ELDS];        //  9,216 B
    __shared__ int   sOff[K_FILT + 1];
    __shared__ int   descLds[MAXG];
    __shared__ int   gc[32];
    __shared__ int   gCount;

    const int t = threadIdx.x;
    const int w = t >> 6;
    const int lane = t & 63;
    const int lrow = lane & 15;
    const int lkB  = (lane >> 4) * 8;
    const int rg4  = (lane >> 4) * 4;

    if (t < K_FILT + 1) sOff[t] = off[bK + t];
    {
        f32x4 z = {0.f, 0.f, 0.f, 0.f};
        f32x4* o4 = reinterpret_cast<f32x4*>(&outT[0][0]);
        for (int j = t; j < RB * 68 / 4; j += 256) o4[j] = z;
    }
    __syncthreads();

    const int blockStart = sOff[0];
    const int total = sOff[K_FILT] - blockStart;
    const int stged = total < ELDS ? total : ELDS;
    for (int i = t; i < stged; i += 256)
        eLds[i] = __builtin_nontemporal_load(&entries[blockStart + i]);

    // parallel descriptor build: (kf<<18 | startJ<<5 | nvalid)
    if (t < K_FILT) gc[t] = (sOff[t + 1] - sOff[t] + 15) >> 4;
    __syncthreads();
    if (t == 0) {
        int s = 0;
        #pragma unroll
        for (int kf = 0; kf < K_FILT; ++kf) { int g = gc[kf]; gc[kf] = s; s += g; }
        gCount = s;
    }
    __syncthreads();
    if (t < K_FILT) {
        int base = sOff[t] - blockStart;
        int c = sOff[t + 1] - sOff[t];
        int s = gc[t];
        for (int j = 0, g = 0; j < c; j += 16, ++g) {
            int nv = c - j; if (nv > 16) nv = 16;
            descLds[s + g] = (t << 18) | ((base + j) << 5) | nv;
        }
    }
    __syncthreads();

    const int nG = gCount;
    const int gOK = useG && (blockStart + total <= PhiCov);
    const __bf16* Gbase = G + (size_t)(blockStart - Plo) * 64;  // valid iff gOK
    int curKf = -1;
    bf16x8 bfrag[4][2];

#define LDENT(idx) ((idx) < stged ? eLds[(idx)] : entries[blockStart + (idx)])

    for (int g = w; g < nG; g += 4) {
        int d = descLds[g];
        int kf = d >> 18, sj = (d >> 5) & 0x1FFF, nv = d & 31;
        if (kf != curKf) {
            curKf = kf;
            const __bf16* wk = wtb + kf * 4096;
            #pragma unroll
            for (int n = 0; n < 4; ++n) {
                bfrag[n][0] = *reinterpret_cast<const bf16x8*>(
                    wk + (n * 16 + lrow) * 64 + lkB);
                bfrag[n][1] = *reinterpret_cast<const bf16x8*>(
                    wk + (n * 16 + lrow) * 64 + 32 + lkB);
            }
        }
        int ja = sj + (lrow < nv ? lrow : 0);
        bf16x8 a0, a1;
        if (gOK) {
            const __bf16* ap = Gbase + (size_t)ja * 64 + lkB;   // sequential
            a0 = *reinterpret_cast<const bf16x8*>(ap);
            a1 = *reinterpret_cast<const bf16x8*>(ap + 32);
        } else {
            int e = LDENT(ja);
            const __bf16* ap = featb + (size_t)(e >> 7) * 64 + lkB;
            a0 = *reinterpret_cast<const bf16x8*>(ap);
            a1 = *reinterpret_cast<const bf16x8*>(ap + 32);
        }

        f32x4 acc[4];
        #pragma unroll
        for (int n = 0; n < 4; ++n) {
            acc[n] = __builtin_amdgcn_mfma_f32_16x16x32_bf16(
                a0, bfrag[n][0], (f32x4){0.f, 0.f, 0.f, 0.f}, 0, 0, 0);
            acc[n] = __builtin_amdgcn_mfma_f32_16x16x32_bf16(
                a1, bfrag[n][1], acc[n], 0, 0, 0);
        }
        #pragma unroll
        for (int r = 0; r < 4; ++r) {
            if (rg4 + r < nv) {
                int eo = LDENT(sj + rg4 + r);
                int ors = eo & 127;
                #pragma unroll
                for (int n = 0; n < 4; ++n)
                    atomicAdd(&outT[ors][n * 16 + lrow], acc[n][r]);
            }
        }
    }
#undef LDENT

    __syncthreads();
    const int rowBase = b * RB;
    for (int j = t; j < RB * 64 / 4; j += 256) {
        int r = j >> 4, c = (j & 15) * 4;
        int gr = rowBase + r;
        if (gr < N_ACTIVE) {
            f32x4 bv = *reinterpret_cast<const f32x4*>(&bias[c]);
            f32x4 v  = *reinterpret_cast<const f32x4*>(&outT[r][c]);
            v += bv;
            __builtin_nontemporal_store(v, reinterpret_cast<f32x4*>(&out[gr * 64 + c]));
        }
    }
}

extern "C" void kernel_launch(void* const* d_in, const int* in_sizes, int n_in,
                              void* d_out, int out_size, void* d_ws, size_t ws_size,
                              hipStream_t stream) {
    const float* feat    = (const float*)d_in[0];
    const float* weight  = (const float*)d_in[1];
    const float* bias    = (const float*)d_in[2];
    const int*   in_idx  = (const int*)d_in[3];
    const int*   out_idx = (const int*)d_in[4];
    float* out = (float*)d_out;

    // ---- fixed workspace layout (G goes last, sized to what's left) ----
    const size_t FB_BYTES = (size_t)N_ACTIVE * 64 * 2;      //  25,600,000
    const size_t WT_BYTES = (size_t)K_FILT * 4096 * 2;      //     221,184
    char* wsb = (char*)d_ws;
    __bf16* featb = (__bf16*)wsb;
    __bf16* wtb   = (__bf16*)(wsb + FB_BYTES);
    int* ip       = (int*)(wsb + FB_BYTES + WT_BYTES);
    int* cntO = ip;                      ip += NBUCK;
    int* cntI = ip;                      ip += N_ACTIVE;     // zeroed with cntO
    int* cursO = ip;                     ip += NBUCK;
    int* cursI = ip;                     ip += N_ACTIVE;
    int* offO = ip;                      ip += NBUCK + 1;
    int* offI = ip;                      ip += N_ACTIVE + 1;
    int* bsumO = ip;                     ip += 256;
    int* bsumI = ip;                     ip += 256;
    int* entries = ip;                   ip += TOTP;
    int* iEnt = ip;                      ip += TOTP;
    size_t fixedBytes = (size_t)((char*)ip - wsb);
    size_t gOffset = (fixedBytes + 255) & ~(size_t)255;
    __bf16* G = (__bf16*)(wsb + gOffset);
    size_t availG = (ws_size > gOffset) ? (ws_size - gOffset) : 0;

    // minimum passes such that (ceil(TOTP/NP)+MARGIN)*128 fits
    int NP = 0;
    for (int p = 1; p <= 24; ++p) {
        size_t need = ((size_t)((TOTP + p - 1) / p) + MARGIN) * 128;
        if (need <= availG) { NP = p; break; }
    }
    const int useG = (NP > 0) ? 1 : 0;

    const int NSB_O = (NBUCK + 1023) / 1024;       // 42
    const int NSB_I = (N_ACTIVE + 1023) / 1024;    // 196

    zero_ints<<<dim3((NBUCK + N_ACTIVE + 255) / 256), dim3(256), 0, stream>>>(
        cntO, NBUCK + N_ACTIVE);
    prep_fused<<<dim3(CF_BLOCKS + CW_BLOCKS + HI_BLOCKS), dim3(256), 0, stream>>>(
        feat, featb, weight, wtb, out_idx, in_idx, cntO, useG ? cntI : nullptr);

    scanA<<<dim3(NSB_O), dim3(256), 0, stream>>>(cntO, offO, bsumO, NBUCK);
    scanB<<<dim3(1), dim3(256), 0, stream>>>(bsumO, NSB_O);
    scanC<<<dim3(NSB_O), dim3(256), 0, stream>>>(offO, bsumO, cursO, NBUCK, TOTP);

    if (useG) {
        scanA<<<dim3(NSB_I), dim3(256), 0, stream>>>(cntI, offI, bsumI, N_ACTIVE);
        scanB<<<dim3(1), dim3(256), 0, stream>>>(bsumI, NSB_I);
        scanC<<<dim3(NSB_I), dim3(256), 0, stream>>>(offI, bsumI, cursI, N_ACTIVE, TOTP);
    }

    scatter_pack<<<dim3((TOTP + 255) / 256), dim3(256), 0, stream>>>(
        in_idx, out_idx, cursO, entries, useG ? cursI : nullptr, useG ? iEnt : nullptr);

    if (useG) {
        const int PQ = (TOTP + NP - 1) / NP;
        for (int p = 0; p < NP; ++p) {
            int Plo = p * PQ;
            int Phi = (Plo + PQ < TOTP) ? Plo + PQ : TOTP;
            int PhiCov = (Phi + MARGIN < TOTP) ? Phi + MARGIN : TOTP;
            gatherG<<<dim3((N_ACTIVE + 31) / 32), dim3(256), 0, stream>>>(
                featb, offI, iEnt, G, Plo, PhiCov);
            conv_dense<<<dim3(NB), dim3(256), 0, stream>>>(
                featb, G, wtb, bias, offO, entries, out, 1, Plo, Phi, PhiCov);
        }
    } else {
        conv_dense<<<dim3(NB), dim3(256), 0, stream>>>(
            featb, featb, wtb, bias, offO, entries, out, 0, 0, TOTP, TOTP);
    }
}